// Round 2
// baseline (13823.582 us; speedup 1.0000x reference)
//
#include <hip/hip_runtime.h>
#include <hip/hip_bf16.h>
#include <math.h>

// ---------------------------------------------------------------------------
// GPT-style transformer forward, fp32 baseline (round 1: ws-size-safe layout).
// L=4, H=12, HD=64, D=768, V=50257, B=1, T=2048
// ---------------------------------------------------------------------------

__global__ __launch_bounds__(256) void k_embed(const int* __restrict__ ids,
                                               const float* __restrict__ emb,
                                               float* __restrict__ x,
                                               int T, int D) {
  int t = blockIdx.x;
  int id = ids[t];
  float neg_log = -logf(10000.0f) / (float)D;
  for (int d = threadIdx.x; d < D; d += 256) {
    float freq = expf((float)(d & ~1) * neg_log);
    float ang = (float)t * freq;
    float pe = (d & 1) ? cosf(ang) : sinf(ang);
    x[(size_t)t * D + d] = emb[(size_t)id * D + d] + pe;
  }
}

__global__ __launch_bounds__(256) void k_layernorm(const float* __restrict__ x,
                                                   const float* __restrict__ g,
                                                   const float* __restrict__ b,
                                                   float* __restrict__ y,
                                                   int D) {
  int t = blockIdx.x;
  const float* xr = x + (size_t)t * D;
  __shared__ float red[256];
  float s = 0.f;
  for (int d = threadIdx.x; d < D; d += 256) s += xr[d];
  red[threadIdx.x] = s;
  __syncthreads();
  for (int st = 128; st > 0; st >>= 1) {
    if (threadIdx.x < st) red[threadIdx.x] += red[threadIdx.x + st];
    __syncthreads();
  }
  float mean = red[0] / (float)D;
  __syncthreads();
  float s2 = 0.f;
  for (int d = threadIdx.x; d < D; d += 256) {
    float u = xr[d] - mean;
    s2 += u * u;
  }
  red[threadIdx.x] = s2;
  __syncthreads();
  for (int st = 128; st > 0; st >>= 1) {
    if (threadIdx.x < st) red[threadIdx.x] += red[threadIdx.x + st];
    __syncthreads();
  }
  float rstd = rsqrtf(red[0] / (float)D + 1e-5f);
  float* yr = y + (size_t)t * D;
  for (int d = threadIdx.x; d < D; d += 256)
    yr[d] = (xr[d] - mean) * rstd * g[d] + b[d];
}

__device__ __forceinline__ float gelu_exact(float v) {
  return 0.5f * v * (1.0f + erff(v * 0.70710678118654752f));
}

// C[M,N] = A[M,K] @ B[N,K]^T + bias[N]  (+res / gelu per mode)
// mode 0: bias only; mode 1: + res[M,N]; mode 2: gelu(acc+bias)
__global__ __launch_bounds__(256) void k_gemm(const float* __restrict__ A,
                                              const float* __restrict__ B,
                                              const float* __restrict__ bias,
                                              const float* __restrict__ res,
                                              float* __restrict__ C,
                                              int M, int N, int K, int mode) {
  __shared__ float As[16][64];
  __shared__ float Bs[16][64];
  int tid = threadIdx.x;
  int tx = tid & 15, ty = tid >> 4;
  int m0 = blockIdx.y << 6, n0 = blockIdx.x << 6;
  int ar = tid >> 2, ac = (tid & 3) << 2;  // loader: row 0..63, k-offset {0,4,8,12}
  float acc[4][4] = {};

  for (int kt = 0; kt < K; kt += 16) {
    float4 av = *(const float4*)(A + (size_t)(m0 + ar) * K + kt + ac);
    float4 bv;
    int brow = n0 + ar;
    if (brow < N)
      bv = *(const float4*)(B + (size_t)brow * K + kt + ac);
    else
      bv = make_float4(0.f, 0.f, 0.f, 0.f);
    As[ac + 0][ar] = av.x; As[ac + 1][ar] = av.y;
    As[ac + 2][ar] = av.z; As[ac + 3][ar] = av.w;
    Bs[ac + 0][ar] = bv.x; Bs[ac + 1][ar] = bv.y;
    Bs[ac + 2][ar] = bv.z; Bs[ac + 3][ar] = bv.w;
    __syncthreads();
#pragma unroll
    for (int k = 0; k < 16; ++k) {
      float4 a = *(const float4*)&As[k][ty << 2];
      float4 b = *(const float4*)&Bs[k][tx << 2];
      acc[0][0] += a.x * b.x; acc[0][1] += a.x * b.y; acc[0][2] += a.x * b.z; acc[0][3] += a.x * b.w;
      acc[1][0] += a.y * b.x; acc[1][1] += a.y * b.y; acc[1][2] += a.y * b.z; acc[1][3] += a.y * b.w;
      acc[2][0] += a.z * b.x; acc[2][1] += a.z * b.y; acc[2][2] += a.z * b.z; acc[2][3] += a.z * b.w;
      acc[3][0] += a.w * b.x; acc[3][1] += a.w * b.y; acc[3][2] += a.w * b.z; acc[3][3] += a.w * b.w;
    }
    __syncthreads();
  }

  int colBase = n0 + (tx << 2);
  if (n0 + 64 <= N) {
    float4 bsv = *(const float4*)(bias + colBase);
#pragma unroll
    for (int i = 0; i < 4; ++i) {
      int row = m0 + (ty << 2) + i;
      float4 r = make_float4(acc[i][0] + bsv.x, acc[i][1] + bsv.y,
                             acc[i][2] + bsv.z, acc[i][3] + bsv.w);
      if (mode == 1) {
        float4 rv = *(const float4*)(res + (size_t)row * N + colBase);
        r.x += rv.x; r.y += rv.y; r.z += rv.z; r.w += rv.w;
      } else if (mode == 2) {
        r.x = gelu_exact(r.x); r.y = gelu_exact(r.y);
        r.z = gelu_exact(r.z); r.w = gelu_exact(r.w);
      }
      *(float4*)(C + (size_t)row * N + colBase) = r;
    }
  } else {
#pragma unroll
    for (int i = 0; i < 4; ++i) {
      int row = m0 + (ty << 2) + i;
#pragma unroll
      for (int j = 0; j < 4; ++j) {
        int col = colBase + j;
        if (col < N) {
          float vvv = acc[i][j] + bias[col];
          if (mode == 1) vvv += res[(size_t)row * N + col];
          else if (mode == 2) vvv = gelu_exact(vvv);
          C[(size_t)row * N + col] = vvv;
        }
      }
    }
  }
}

// One wave per (head, query row): online-softmax causal attention.
// q,k,v,ctx are [T, H*HD] with head h occupying cols h*64..h*64+63.
__global__ __launch_bounds__(256) void k_attn(const float* __restrict__ q,
                                              const float* __restrict__ k,
                                              const float* __restrict__ v,
                                              float* __restrict__ ctx,
                                              int T, int D, float scale) {
  int lane = threadIdx.x & 63;
  int wid = threadIdx.x >> 6;
  int t = (blockIdx.x << 2) + wid;
  int h = blockIdx.y;
  if (t >= T) return;
  int hoff = h << 6;
  float ql = q[(size_t)t * D + hoff + lane];
  float m = -1e30f, l = 0.f, o = 0.f;
  for (int s = 0; s <= t; ++s) {
    float p = ql * k[(size_t)s * D + hoff + lane];
    p += __shfl_xor(p, 32, 64);
    p += __shfl_xor(p, 16, 64);
    p += __shfl_xor(p, 8, 64);
    p += __shfl_xor(p, 4, 64);
    p += __shfl_xor(p, 2, 64);
    p += __shfl_xor(p, 1, 64);
    float score = p * scale;
    float mnew = fmaxf(m, score);
    float alpha = __expf(m - mnew);
    float w = __expf(score - mnew);
    o = o * alpha + w * v[(size_t)s * D + hoff + lane];
    l = l * alpha + w;
    m = mnew;
  }
  ctx[(size_t)t * D + hoff + lane] = o / l;
}

extern "C" void kernel_launch(void* const* d_in, const int* in_sizes, int n_in,
                              void* d_out, int out_size, void* d_ws, size_t ws_size,
                              hipStream_t stream) {
  const int T = 2048, D = 768, H = 12, L = 4, V = 50257, D4 = 3072;
  const size_t td = (size_t)T * D;

  const int* ids      = (const int*)d_in[0];
  const float* emb    = (const float*)d_in[1];
  const float* lm_bias= (const float*)d_in[2];
  const float* ln1_g  = (const float*)d_in[3];
  const float* ln1_b  = (const float*)d_in[4];
  const float* ln2_g  = (const float*)d_in[5];
  const float* ln2_b  = (const float*)d_in[6];
  const float* Wq     = (const float*)d_in[7];
  const float* bq     = (const float*)d_in[8];
  const float* Wk     = (const float*)d_in[9];
  const float* bk     = (const float*)d_in[10];
  const float* Wv     = (const float*)d_in[11];
  const float* bv     = (const float*)d_in[12];
  const float* Wo     = (const float*)d_in[13];
  const float* bo     = (const float*)d_in[14];
  const float* W1     = (const float*)d_in[15];
  const float* b1     = (const float*)d_in[16];
  const float* W2     = (const float*)d_in[17];
  const float* b2     = (const float*)d_in[18];
  const float* lnf_g  = (const float*)d_in[19];
  const float* lnf_b  = (const float*)d_in[20];
  float* out = (float*)d_out;

  // Scratch layout, adapted to ws_size (round-1 fix: round 0 assumed 6*T*D
  // fp32 in d_ws = 37.75 MB and overflowed, corrupting adjacent allocations,
  // which showed up as post-timing divergence after the harness restored
  // inputs from its corrupted pristine copies).
  //   x, xn           -> d_ws          (2*T*D fp32 = 12.6 MB)
  //   q,k,v,ctx / MLP -> tail of d_out (4*T*D fp32 = 25.2 MB) unless d_ws is
  //                      big enough. Tail scratch is dead before the final
  //                      LM-head GEMM overwrites d_out; its input xn is in
  //                      d_ws, so no read/write race.
  float* x  = (float*)d_ws;
  float* xn = x + td;
  float* qb;
  if (ws_size >= (size_t)6 * td * sizeof(float)) {
    qb = xn + td;
  } else {
    qb = out + ((size_t)out_size - 4 * td);  // out_size*4B aligned tail
  }
  float* kb = qb + td;
  float* vb = kb + td;
  float* cb = vb + td;
  float* hb = qb;  // [T, 4D] aliases q,k,v,ctx (dead during MLP)

  dim3 blk(256);
  k_embed<<<T, blk, 0, stream>>>(ids, emb, x, T, D);

  for (int l = 0; l < L; ++l) {
    k_layernorm<<<T, blk, 0, stream>>>(x, ln1_g + l * D, ln1_b + l * D, xn, D);

    dim3 gqkv(D / 64, T / 64);
    k_gemm<<<gqkv, blk, 0, stream>>>(xn, Wq + (size_t)l * D * D, bq + l * D, nullptr, qb, T, D, D, 0);
    k_gemm<<<gqkv, blk, 0, stream>>>(xn, Wk + (size_t)l * D * D, bk + l * D, nullptr, kb, T, D, D, 0);
    k_gemm<<<gqkv, blk, 0, stream>>>(xn, Wv + (size_t)l * D * D, bv + l * D, nullptr, vb, T, D, D, 0);

    dim3 ga(T / 4, H);
    k_attn<<<ga, blk, 0, stream>>>(qb, kb, vb, cb, T, D, 0.125f);

    k_gemm<<<gqkv, blk, 0, stream>>>(cb, Wo + (size_t)l * D * D, bo + l * D, x, x, T, D, D, 1);

    k_layernorm<<<T, blk, 0, stream>>>(x, ln2_g + l * D, ln2_b + l * D, xn, D);

    dim3 g1(D4 / 64, T / 64);
    k_gemm<<<g1, blk, 0, stream>>>(xn, W1 + (size_t)l * D4 * D, b1 + l * D4, nullptr, hb, T, D4, D, 2);

    dim3 g2(D / 64, T / 64);
    k_gemm<<<g2, blk, 0, stream>>>(hb, W2 + (size_t)l * D * D4, b2 + l * D, x, x, T, D, D4, 1);
  }

  k_layernorm<<<T, blk, 0, stream>>>(x, lnf_g, lnf_b, xn, D);

  dim3 gl((V + 63) / 64, T / 64);
  k_gemm<<<gl, blk, 0, stream>>>(xn, emb, lm_bias, nullptr, out, T, V, D, 0);
}